// Round 1
// baseline (6024.197 us; speedup 1.0000x reference)
//
#include <hip/hip_runtime.h>

#define HW 16384
#define EPSF 1e-5f

// ---------------- BN folding: alpha = g*rsqrt(v+eps); beta = (bias-m)*alpha + be
__global__ void bn_prep(const float* __restrict__ b1, const float* __restrict__ g1,
                        const float* __restrict__ be1, const float* __restrict__ m1,
                        const float* __restrict__ v1,
                        const float* __restrict__ b2, const float* __restrict__ g2,
                        const float* __restrict__ be2, const float* __restrict__ m2,
                        const float* __restrict__ v2,
                        const float* __restrict__ b3, const float* __restrict__ g3,
                        const float* __restrict__ be3, const float* __restrict__ m3,
                        const float* __restrict__ v3,
                        float* __restrict__ ws) {
    int t = threadIdx.x;
    if (t < 256) { float a = g1[t] * rsqrtf(v1[t] + EPSF); ws[t] = a;       ws[256 + t] = (b1[t] - m1[t]) * a + be1[t]; }
    if (t < 128) { float a = g2[t] * rsqrtf(v2[t] + EPSF); ws[512 + t] = a; ws[640 + t] = (b2[t] - m2[t]) * a + be2[t]; }
    if (t < 64)  { float a = g3[t] * rsqrtf(v3[t] + EPSF); ws[768 + t] = a; ws[832 + t] = (b3[t] - m3[t]) * a + be3[t]; }
}

// ---------------- concat part 1: out[b, 0:64] = input[b]
__global__ __launch_bounds__(256) void copy_in_k(const float* __restrict__ x, float* __restrict__ out) {
    size_t i = (size_t)blockIdx.x * 256 + threadIdx.x;   // float4 index; total 16*64*HW/4 = 4194304
    size_t b = i >> 18;                 // 64*HW/4 = 262144 float4 per batch
    size_t r = i & 262143;
    ((float4*)out)[b * (size_t)(128 * HW / 4) + r] = ((const float4*)x)[i];
}

// ---------------- conv1x1 (64 -> 256) + BN + ReLU. 4 px (float4) x 8 co per thread.
__global__ __launch_bounds__(256)
void conv1_k(const float* __restrict__ x, const float* __restrict__ w,
             const float* __restrict__ alpha, const float* __restrict__ beta,
             float* __restrict__ y, int b0) {
    const int tid = threadIdx.x;
    const int p = (blockIdx.x * 256 + tid) * 4;   // pixel base
    const int cog = blockIdx.y;                   // 32 groups of 8 co
    const int bz = blockIdx.z;
    const float* xb = x + ((size_t)(b0 + bz) * 64) * HW + p;
    float4 acc[8];
#pragma unroll
    for (int j = 0; j < 8; ++j) acc[j] = make_float4(0.f, 0.f, 0.f, 0.f);
#pragma unroll 4
    for (int ci = 0; ci < 64; ++ci) {
        const float4 xv = *(const float4*)(xb + (size_t)ci * HW);
#pragma unroll
        for (int j = 0; j < 8; ++j) {
            const float wv = w[(cog * 8 + j) * 64 + ci];
            acc[j].x += wv * xv.x; acc[j].y += wv * xv.y;
            acc[j].z += wv * xv.z; acc[j].w += wv * xv.w;
        }
    }
#pragma unroll
    for (int j = 0; j < 8; ++j) {
        const int co = cog * 8 + j;
        const float a = alpha[co], be = beta[co];
        float4 o;
        o.x = fmaxf(acc[j].x * a + be, 0.f);
        o.y = fmaxf(acc[j].y * a + be, 0.f);
        o.z = fmaxf(acc[j].z * a + be, 0.f);
        o.w = fmaxf(acc[j].w * a + be, 0.f);
        *(float4*)(y + ((size_t)bz * 256 + co) * HW + p) = o;
    }
}

// ---------------- generic 3x3 conv + BN + ReLU (cross-correlation, pad=1)
// block: 256 threads = 16x16 spatial tile; each thread accumulates CO_TILE out-channels.
template <int CIN, int CO_TILE, int CI_CHUNK>
__global__ __launch_bounds__(256)
void conv3x3_k(const float* __restrict__ x, const float* __restrict__ w,
               const float* __restrict__ alpha, const float* __restrict__ beta,
               float* __restrict__ y, size_t ybstride, int yco_off) {
    __shared__ float sx[CI_CHUNK][18 * 18];
    const int tid = threadIdx.x;
    const int tx = tid & 15, ty = tid >> 4;
    const int x0 = (blockIdx.x & 7) * 16, y0 = (blockIdx.x >> 3) * 16;
    const int cog = blockIdx.y;
    const int bz = blockIdx.z;
    const float* xb = x + (size_t)bz * CIN * HW;

    float acc[CO_TILE];
#pragma unroll
    for (int j = 0; j < CO_TILE; ++j) acc[j] = 0.f;

    for (int cc = 0; cc < CIN; cc += CI_CHUNK) {
        __syncthreads();
        for (int i = tid; i < CI_CHUNK * 324; i += 256) {
            const int ci = i / 324, r = i - ci * 324;
            const int iy = r / 18, ix = r - iy * 18;
            const int gy = y0 + iy - 1, gx = x0 + ix - 1;
            float v = 0.f;
            if ((unsigned)gy < 128u && (unsigned)gx < 128u)
                v = xb[(size_t)(cc + ci) * HW + gy * 128 + gx];
            sx[ci][r] = v;
        }
        __syncthreads();
#pragma unroll
        for (int ci = 0; ci < CI_CHUNK; ++ci) {
            const float n0 = sx[ci][(ty + 0) * 18 + tx + 0];
            const float n1 = sx[ci][(ty + 0) * 18 + tx + 1];
            const float n2 = sx[ci][(ty + 0) * 18 + tx + 2];
            const float n3 = sx[ci][(ty + 1) * 18 + tx + 0];
            const float n4 = sx[ci][(ty + 1) * 18 + tx + 1];
            const float n5 = sx[ci][(ty + 1) * 18 + tx + 2];
            const float n6 = sx[ci][(ty + 2) * 18 + tx + 0];
            const float n7 = sx[ci][(ty + 2) * 18 + tx + 1];
            const float n8 = sx[ci][(ty + 2) * 18 + tx + 2];
            const float* wp = w + ((size_t)cog * CO_TILE * CIN + (cc + ci)) * 9;
#pragma unroll
            for (int j = 0; j < CO_TILE; ++j) {
                const float* wj = wp + (size_t)j * CIN * 9;
                float s = acc[j];
                s += wj[0] * n0; s += wj[1] * n1; s += wj[2] * n2;
                s += wj[3] * n3; s += wj[4] * n4; s += wj[5] * n5;
                s += wj[6] * n6; s += wj[7] * n7; s += wj[8] * n8;
                acc[j] = s;
            }
        }
    }
    const int px = (y0 + ty) * 128 + (x0 + tx);
#pragma unroll
    for (int j = 0; j < CO_TILE; ++j) {
        const int co = cog * CO_TILE + j;
        const float o = fmaxf(acc[j] * alpha[co] + beta[co], 0.f);
        y[(size_t)bz * ybstride + (size_t)(yco_off + co) * HW + px] = o;
    }
}

// ---------------- sobel depthwise (fixed summed kernel), pad=1
__global__ __launch_bounds__(256)
void sobel_k(const float* __restrict__ x, float* __restrict__ y) {
    const int t = blockIdx.x * 256 + threadIdx.x;   // pixel within plane
    const int plane = blockIdx.y;
    const int py = t >> 7, px = t & 127;
    const float* xp = x + (size_t)plane * HW;
    auto L = [&](int yy, int xx) -> float {
        return ((unsigned)yy < 128u && (unsigned)xx < 128u) ? xp[yy * 128 + xx] : 0.f;
    };
    // SOBEL_SUM = [[2,4,4],[-2,0,2],[-4,-4,-2]]
    float s = 2.f * L(py - 1, px - 1) + 4.f * L(py - 1, px) + 4.f * L(py - 1, px + 1)
            - 2.f * L(py,     px - 1)                       + 2.f * L(py,     px + 1)
            - 4.f * L(py + 1, px - 1) - 4.f * L(py + 1, px) - 2.f * L(py + 1, px + 1);
    y[(size_t)plane * HW + t] = s;
}

extern "C" void kernel_launch(void* const* d_in, const int* in_sizes, int n_in,
                              void* d_out, int out_size, void* d_ws, size_t ws_size,
                              hipStream_t stream) {
    const float* input = (const float*)d_in[0];
    const float* w1 = (const float*)d_in[1];
    const float* b1 = (const float*)d_in[2];
    const float* g1 = (const float*)d_in[3];
    const float* be1 = (const float*)d_in[4];
    const float* m1 = (const float*)d_in[5];
    const float* v1 = (const float*)d_in[6];
    const float* w2 = (const float*)d_in[7];
    const float* b2 = (const float*)d_in[8];
    const float* g2 = (const float*)d_in[9];
    const float* be2 = (const float*)d_in[10];
    const float* m2 = (const float*)d_in[11];
    const float* v2 = (const float*)d_in[12];
    const float* w3 = (const float*)d_in[13];
    const float* b3 = (const float*)d_in[14];
    const float* g3 = (const float*)d_in[15];
    const float* be3 = (const float*)d_in[16];
    const float* m3 = (const float*)d_in[17];
    const float* v3 = (const float*)d_in[18];
    float* ws = (float*)d_ws;
    float* out = (float*)d_out;

    float* A1 = ws;        float* B1 = ws + 256;
    float* A2 = ws + 512;  float* B2 = ws + 640;
    float* A3 = ws + 768;  float* B3 = ws + 832;

    // batch-chunked scratch: c1 (256ch) + c2 (128ch) per batch; edge reuses c1 region
    const size_t base = 1024;
    const size_t per_b_floats = (size_t)(256 + 128) * HW;   // 6.29M floats = 25.2 MB
    size_t avail = (ws_size / 4 > base) ? (ws_size / 4 - base) : 0;
    int nb = (int)(avail / per_b_floats);
    if (nb > 16) nb = 16;
    if (nb < 1) nb = 1;   // requires ~25.2 MB of ws
    float* c1 = ws + base;
    float* c2 = c1 + (size_t)nb * 256 * HW;
    float* edge = c1;     // c1 fully consumed by conv2 before sobel writes

    bn_prep<<<1, 256, 0, stream>>>(b1, g1, be1, m1, v1, b2, g2, be2, m2, v2,
                                   b3, g3, be3, m3, v3, ws);
    copy_in_k<<<16384, 256, 0, stream>>>(input, out);

    for (int b0 = 0; b0 < 16; b0 += nb) {
        int n = (16 - b0 < nb) ? (16 - b0) : nb;
        conv1_k<<<dim3(16, 32, n), 256, 0, stream>>>(input, w1, A1, B1, c1, b0);
        conv3x3_k<256, 16, 8><<<dim3(64, 8, n), 256, 0, stream>>>(
            c1, w2, A2, B2, c2, (size_t)128 * HW, 0);
        sobel_k<<<dim3(64, n * 128), 256, 0, stream>>>(c2, edge);
        conv3x3_k<128, 16, 8><<<dim3(64, 4, n), 256, 0, stream>>>(
            edge, w3, A3, B3, out + (size_t)b0 * 128 * HW, (size_t)128 * HW, 64);
    }
}

// Round 3
// 950.473 us; speedup vs baseline: 6.3381x; 6.3381x over previous
//
#include <hip/hip_runtime.h>

#define HW 16384
#define EPSF 1e-5f

typedef __attribute__((ext_vector_type(8))) short s8v;     // 8 bf16 (4 VGPRs)
typedef __attribute__((ext_vector_type(16))) float f16v;   // 32x32 accum

__device__ __forceinline__ ushort f2b(float f) {           // fp32 -> bf16 RNE
    union { float f; unsigned u; } v; v.f = f;
    return (ushort)((v.u + 0x7FFFu + ((v.u >> 16) & 1u)) >> 16);
}

// ---------------- BN folding
__global__ void bn_prep(const float* __restrict__ b1, const float* __restrict__ g1,
                        const float* __restrict__ be1, const float* __restrict__ m1,
                        const float* __restrict__ v1,
                        const float* __restrict__ b2, const float* __restrict__ g2,
                        const float* __restrict__ be2, const float* __restrict__ m2,
                        const float* __restrict__ v2,
                        const float* __restrict__ b3, const float* __restrict__ g3,
                        const float* __restrict__ be3, const float* __restrict__ m3,
                        const float* __restrict__ v3,
                        float* __restrict__ ws) {
    int t = threadIdx.x;
    if (t < 256) { float a = g1[t] * rsqrtf(v1[t] + EPSF); ws[t] = a;       ws[256 + t] = (b1[t] - m1[t]) * a + be1[t]; }
    if (t < 128) { float a = g2[t] * rsqrtf(v2[t] + EPSF); ws[512 + t] = a; ws[640 + t] = (b2[t] - m2[t]) * a + be2[t]; }
    if (t < 64)  { float a = g3[t] * rsqrtf(v3[t] + EPSF); ws[768 + t] = a; ws[832 + t] = (b3[t] - m3[t]) * a + be3[t]; }
}

// ---------------- weight repack fp32 OIHW -> bf16 [off][co][ci]
__global__ __launch_bounds__(256) void wprep(const float* __restrict__ w2, const float* __restrict__ w3,
                                             ushort* __restrict__ w2b, ushort* __restrict__ w3b) {
    int t = blockIdx.x * 256 + threadIdx.x;
    if (t < 9 * 128 * 256) {
        int off = t >> 15; int r = t & 32767; int co = r >> 8; int ci = r & 255;
        w2b[t] = f2b(w2[(co * 256 + ci) * 9 + off]);
    }
    t -= 9 * 128 * 256;
    if (t >= 0 && t < 9 * 64 * 128) {
        int off = t >> 13; int r = t & 8191; int co = r >> 7; int ci = r & 127;
        w3b[t] = f2b(w3[(co * 128 + ci) * 9 + off]);
    }
}

// ---------------- concat part 1: out[b, 0:64] = input[b]
__global__ __launch_bounds__(256) void copy_in_k(const float* __restrict__ x, float* __restrict__ out) {
    size_t i = (size_t)blockIdx.x * 256 + threadIdx.x;
    size_t b = i >> 18;
    size_t r = i & 262143;
    ((float4*)out)[b * (size_t)(128 * HW / 4) + r] = ((const float4*)x)[i];
}

// ---------------- conv1x1 (64 -> 256) + BN + ReLU, fp32 math, NHWC bf16 out (batch chunk)
__global__ __launch_bounds__(256)
void conv1_nhwc(const float* __restrict__ x, const float* __restrict__ w,
                const float* __restrict__ alpha, const float* __restrict__ beta,
                ushort* __restrict__ c1b, int b0) {
    const int tid = threadIdx.x;
    const int pg = tid & 31;        // 4-px group
    const int cog = tid >> 5;       // 8-co group
    const int y = blockIdx.x & 127;
    const int coblk = blockIdx.x >> 7;   // 0..3
    const int bz = blockIdx.y;           // chunk-local batch
    const int co0 = coblk * 64 + cog * 8;
    const float* xp = x + (size_t)(b0 + bz) * 64 * HW + y * 128 + pg * 4;
    float acc[8][4];
#pragma unroll
    for (int j = 0; j < 8; ++j)
#pragma unroll
        for (int i = 0; i < 4; ++i) acc[j][i] = 0.f;
#pragma unroll 4
    for (int ci = 0; ci < 64; ++ci) {
        const float4 xv = *(const float4*)(xp + (size_t)ci * HW);
#pragma unroll
        for (int j = 0; j < 8; ++j) {
            const float wv = w[(co0 + j) * 64 + ci];
            acc[j][0] += wv * xv.x; acc[j][1] += wv * xv.y;
            acc[j][2] += wv * xv.z; acc[j][3] += wv * xv.w;
        }
    }
    const float4 a0 = *(const float4*)&alpha[co0], a1 = *(const float4*)&alpha[co0 + 4];
    const float4 b0v = *(const float4*)&beta[co0], b1v = *(const float4*)&beta[co0 + 4];
    const float av[8] = {a0.x, a0.y, a0.z, a0.w, a1.x, a1.y, a1.z, a1.w};
    const float bv[8] = {b0v.x, b0v.y, b0v.z, b0v.w, b1v.x, b1v.y, b1v.z, b1v.w};
#pragma unroll
    for (int i = 0; i < 4; ++i) {
        union { ushort s[8]; int4 v; } o;
#pragma unroll
        for (int j = 0; j < 8; ++j)
            o.s[j] = f2b(fmaxf(acc[j][i] * av[j] + bv[j], 0.f));
        const int xx = pg * 4 + i;
        *(int4*)&c1b[(((size_t)bz * 128 + y) * 128 + xx) * 256 + co0] = o.v;
    }
}

// ---------------- conv2: 3x3, 256->128, implicit-GEMM MFMA (bf16), writes c2 bf16
// into the out[b,64:128] region: ybf + ((batch*128+64)*HW)*2 + ((y*128+x)*128 + co).
__global__ __launch_bounds__(256, 2)
void conv2_mfma(const ushort* __restrict__ xb, const ushort* __restrict__ wb,
                const float* __restrict__ alpha, const float* __restrict__ beta,
                ushort* __restrict__ ybf, int b0) {
    constexpr int CI = 256, CO = 128, MT = 2;
    __shared__ __align__(16) ushort sX[2][130][40];   // [row][px+1][ci32 pad40]
    __shared__ __align__(16) ushort sW[CO][40];
    const int tid = threadIdx.x;
    const int lane = tid & 63;
    const int wid = tid >> 6;
    const int wm = wid & 1;
    const int wr = wid >> 1;
    const int l31 = lane & 31;
    const int l5 = lane >> 5;
    const int bz = blockIdx.x >> 6;                   // chunk-local batch
    const int y0 = (blockIdx.x & 63) * 2;

    f16v acc[MT][4];
#pragma unroll
    for (int mt = 0; mt < MT; ++mt)
#pragma unroll
        for (int nt = 0; nt < 4; ++nt) acc[mt][nt] = (f16v)(0.0f);

    if (tid < 160) {       // zero x-halo pads once
        int r = tid / 80, rem = tid - r * 80;
        int p = (rem < 40) ? 0 : 129;
        sX[r][p][rem % 40] = 0;
    }

    for (int dy = 0; dy < 3; ++dy) {
        for (int cc = 0; cc < CI; cc += 32) {
            __syncthreads();
#pragma unroll
            for (int it = 0; it < 4; ++it) {
                const int idx = it * 256 + tid;
                const int r = idx >> 9, xx = (idx >> 2) & 127, cig = idx & 3;
                const int yy = y0 + r + dy - 1;
                int4 v = make_int4(0, 0, 0, 0);
                if ((unsigned)yy < 128u)
                    v = *(const int4*)&xb[((((size_t)bz * 128 + yy) * 128) + xx) * CI + cc + cig * 8];
                *(int4*)&sX[r][xx + 1][cig * 8] = v;
            }
            for (int dx = 0; dx < 3; ++dx) {
                if (dx) __syncthreads();
                const int off = dy * 3 + dx;
#pragma unroll
                for (int it = 0; it < 2; ++it) {
                    const int idx = it * 256 + tid;
                    const int co = idx >> 2, cig = idx & 3;
                    *(int4*)&sW[co][cig * 8] =
                        *(const int4*)&wb[((size_t)(off * CO) + co) * CI + cc + cig * 8];
                }
                __syncthreads();
#pragma unroll
                for (int kh = 0; kh < 2; ++kh) {
                    s8v af[MT], bfr[4];
#pragma unroll
                    for (int mt = 0; mt < MT; ++mt)
                        af[mt] = *(const s8v*)&sW[wm * 64 + mt * 32 + l31][kh * 16 + l5 * 8];
#pragma unroll
                    for (int nt = 0; nt < 4; ++nt)
                        bfr[nt] = *(const s8v*)&sX[wr][nt * 32 + l31 + dx][kh * 16 + l5 * 8];
#pragma unroll
                    for (int mt = 0; mt < MT; ++mt)
#pragma unroll
                        for (int nt = 0; nt < 4; ++nt)
                            acc[mt][nt] = __builtin_amdgcn_mfma_f32_32x32x16_bf16(
                                af[mt], bfr[nt], acc[mt][nt], 0, 0, 0);
                }
            }
        }
    }
    // epilogue -> bf16 NHWC c2 plane inside d_out (batch b0+bz, channels 64:128 region)
    const int yy = y0 + wr;
    const size_t cb2 = (((size_t)(b0 + bz) * 128 + 64) * (size_t)HW) * 2;
#pragma unroll
    for (int mt = 0; mt < MT; ++mt) {
#pragma unroll
        for (int nt = 0; nt < 4; ++nt) {
            const int xx = nt * 32 + l31;
#pragma unroll
            for (int rg = 0; rg < 4; ++rg) {
                const int co0 = wm * 64 + mt * 32 + rg * 8 + l5 * 4;
                const float4 av = *(const float4*)&alpha[co0];
                const float4 bv = *(const float4*)&beta[co0];
                ushort4 o;
                o.x = f2b(fmaxf(acc[mt][nt][rg * 4 + 0] * av.x + bv.x, 0.f));
                o.y = f2b(fmaxf(acc[mt][nt][rg * 4 + 1] * av.y + bv.y, 0.f));
                o.z = f2b(fmaxf(acc[mt][nt][rg * 4 + 2] * av.z + bv.z, 0.f));
                o.w = f2b(fmaxf(acc[mt][nt][rg * 4 + 3] * av.w + bv.w, 0.f));
                *(ushort4*)&ybf[cb2 + ((size_t)yy * 128 + xx) * 128 + co0] = o;
            }
        }
    }
}

__device__ __forceinline__ void fma8(float* a, const int4 v, float c) {
    const unsigned* u = (const unsigned*)&v;
#pragma unroll
    for (int q = 0; q < 4; ++q) {
        union { unsigned x; float f; } lo, hi;
        lo.x = u[q] << 16; hi.x = u[q] & 0xffff0000u;
        a[2 * q]     += c * lo.f;
        a[2 * q + 1] += c * hi.f;
    }
}

// ---------------- fused sobel + conv3 (128->64, 3x3, pad 1) -> fp32 NCHW ping chunk
// c2 read from out[b,64:128] region (bf16 NHWC); edge computed in LDS per 32-ci slab.
__global__ __launch_bounds__(256)
void sobel_conv3(const ushort* __restrict__ c2u, const ushort* __restrict__ wb,
                 const float* __restrict__ alpha, const float* __restrict__ beta,
                 float* __restrict__ ping, int b0) {
    __shared__ __align__(16) ushort sE[4][130][40];   // edge rows y0-1..y0+2, px x+1 (0..129), 32ci pad40
    const int tid = threadIdx.x;
    const int lane = tid & 63;
    const int wid = tid >> 6;
    const int wm = wid & 1;        // co half (32)
    const int wr = wid >> 1;       // out row
    const int l31 = lane & 31;
    const int l5 = lane >> 5;
    const int bz = blockIdx.x >> 6;
    const int y0 = (blockIdx.x & 63) * 2;
    const size_t cb2 = (((size_t)(b0 + bz) * 128 + 64) * (size_t)HW) * 2;

    f16v acc[4];
#pragma unroll
    for (int nt = 0; nt < 4; ++nt) acc[nt] = (f16v)(0.0f);

    const float cf[9] = {2.f, 4.f, 4.f, -2.f, 0.f, 2.f, -4.f, -4.f, -2.f};

    for (int cc = 0; cc < 128; cc += 32) {
        __syncthreads();   // prior MFMA reads of sE complete
        // compute edge slab: 4 rows x 130 px x 4 ci-groups(8) = 2080 int4 tasks
        for (int it = 0; it < 9; ++it) {
            const int idx = it * 256 + tid;
            if (idx < 2080) {
                const int r = idx / 520;
                const int rem = idx - r * 520;
                const int xx = rem >> 2, cig = rem & 3;
                const int ey = y0 + r - 1, ex = xx - 1;
                float a8[8];
#pragma unroll
                for (int j = 0; j < 8; ++j) a8[j] = 0.f;
                if ((unsigned)ey < 128u && (unsigned)ex < 128u) {
#pragma unroll
                    for (int t = 0; t < 9; ++t) {
                        if (t == 4) continue;
                        const int cy = ey + t / 3 - 1, cx = ex + t % 3 - 1;
                        if ((unsigned)cy < 128u && (unsigned)cx < 128u) {
                            const int4 v = *(const int4*)&c2u[cb2 + ((size_t)cy * 128 + cx) * 128 + cc + cig * 8];
                            fma8(a8, v, cf[t]);
                        }
                    }
                }
                union { ushort s[8]; int4 v; } o;
#pragma unroll
                for (int j = 0; j < 8; ++j) o.s[j] = f2b(a8[j]);
                *(int4*)&sE[r][xx][cig * 8] = o.v;
            }
        }
        __syncthreads();
        // MFMA: A from global w3b, B from sE
#pragma unroll
        for (int off = 0; off < 9; ++off) {
            const int dy = off / 3, dx = off % 3;
#pragma unroll
            for (int kh = 0; kh < 2; ++kh) {
                const s8v af = *(const s8v*)&wb[((size_t)(off * 64) + wm * 32 + l31) * 128 + cc + kh * 16 + l5 * 8];
                s8v bfr[4];
#pragma unroll
                for (int nt = 0; nt < 4; ++nt)
                    bfr[nt] = *(const s8v*)&sE[wr + dy][nt * 32 + l31 + dx][kh * 16 + l5 * 8];
#pragma unroll
                for (int nt = 0; nt < 4; ++nt)
                    acc[nt] = __builtin_amdgcn_mfma_f32_32x32x16_bf16(af, bfr[nt], acc[nt], 0, 0, 0);
            }
        }
    }
    // epilogue -> ping [bz][64][HW] fp32 NCHW
    const int yy = y0 + wr;
#pragma unroll
    for (int nt = 0; nt < 4; ++nt) {
        const int xx = nt * 32 + l31;
#pragma unroll
        for (int rg = 0; rg < 4; ++rg) {
            const int co0 = wm * 32 + rg * 8 + l5 * 4;
            const float4 av = *(const float4*)&alpha[co0];
            const float4 bv = *(const float4*)&beta[co0];
            const size_t base = ((size_t)bz * 64 + co0) * HW + yy * 128 + xx;
            ping[base]          = fmaxf(acc[nt][rg * 4 + 0] * av.x + bv.x, 0.f);
            ping[base + HW]     = fmaxf(acc[nt][rg * 4 + 1] * av.y + bv.y, 0.f);
            ping[base + 2 * HW] = fmaxf(acc[nt][rg * 4 + 2] * av.z + bv.z, 0.f);
            ping[base + 3 * HW] = fmaxf(acc[nt][rg * 4 + 3] * av.w + bv.w, 0.f);
        }
    }
}

// ---------------- copy ping -> out[b,64:128]
__global__ __launch_bounds__(256) void copy3_k(const float* __restrict__ ping, float* __restrict__ out, int b0) {
    const size_t idx = (size_t)blockIdx.x * 256 + threadIdx.x;    // float4 idx; 262144/batch
    const size_t bz = idx >> 18;
    const size_t rem = idx & 262143;
    ((float4*)out)[((size_t)(b0 + bz) * 128 + 64) * 4096 + rem] = ((const float4*)ping)[idx];
}

extern "C" void kernel_launch(void* const* d_in, const int* in_sizes, int n_in,
                              void* d_out, int out_size, void* d_ws, size_t ws_size,
                              hipStream_t stream) {
    const float* input = (const float*)d_in[0];
    const float* w1 = (const float*)d_in[1];
    const float* b1 = (const float*)d_in[2];
    const float* g1 = (const float*)d_in[3];
    const float* be1 = (const float*)d_in[4];
    const float* m1 = (const float*)d_in[5];
    const float* v1 = (const float*)d_in[6];
    const float* w2 = (const float*)d_in[7];
    const float* b2 = (const float*)d_in[8];
    const float* g2 = (const float*)d_in[9];
    const float* be2 = (const float*)d_in[10];
    const float* m2 = (const float*)d_in[11];
    const float* v2 = (const float*)d_in[12];
    const float* w3 = (const float*)d_in[13];
    const float* b3 = (const float*)d_in[14];
    const float* g3 = (const float*)d_in[15];
    const float* be3 = (const float*)d_in[16];
    const float* m3 = (const float*)d_in[17];
    const float* v3 = (const float*)d_in[18];
    float* ws = (float*)d_ws;
    float* out = (float*)d_out;

    float* A1 = ws;        float* B1 = ws + 256;
    float* A2 = ws + 512;  float* B2 = ws + 640;
    float* A3 = ws + 768;  float* B3 = ws + 832;

    char* wsb = (char*)d_ws;
    ushort* w2b = (ushort*)(wsb + 4096);                 // 589824 B
    ushort* w3b = (ushort*)(wsb + 4096 + 589824);        // 147456 B -> ends at 741376
    char* dynb = wsb + 741376;

    // adaptive chunking within the PROVEN >=25.2 MB workspace
    const size_t dyn = (ws_size > 741376) ? ws_size - 741376 : 0;
    int nb1 = (int)(dyn / 8388608);   // c1b: 8 MB per batch (bf16 NHWC 256ch)
    if (nb1 < 1) nb1 = 1; if (nb1 > 16) nb1 = 16;
    int nb3 = (int)(dyn / 4194304);   // ping: 4 MB per batch (fp32 64ch)
    if (nb3 < 1) nb3 = 1; if (nb3 > 16) nb3 = 16;
    ushort* c1b = (ushort*)dynb;
    float* ping = (float*)dynb;       // reused after phase A

    bn_prep<<<1, 256, 0, stream>>>(b1, g1, be1, m1, v1, b2, g2, be2, m2, v2,
                                   b3, g3, be3, m3, v3, ws);
    wprep<<<1440, 256, 0, stream>>>(w2, w3, w2b, w3b);
    copy_in_k<<<16384, 256, 0, stream>>>(input, out);

    // phase A: conv1 -> c1b (ws chunk), conv2 -> c2 bf16 inside out[b,64:]
    for (int b0 = 0; b0 < 16; b0 += nb1) {
        const int n = (16 - b0 < nb1) ? (16 - b0) : nb1;
        conv1_nhwc<<<dim3(512, n), 256, 0, stream>>>(input, w1, A1, B1, c1b, b0);
        conv2_mfma<<<n * 64, 256, 0, stream>>>(c1b, w2b, A2, B2, (ushort*)d_out, b0);
    }
    // phase B: fused sobel+conv3 -> ping (ws chunk), then copy into out[b,64:]
    for (int b0 = 0; b0 < 16; b0 += nb3) {
        const int n = (16 - b0 < nb3) ? (16 - b0) : nb3;
        sobel_conv3<<<n * 64, 256, 0, stream>>>((const ushort*)d_out, w3b, A3, B3, ping, b0);
        copy3_k<<<n * 1024, 256, 0, stream>>>(ping, out, b0);
    }
}

// Round 4
// 710.283 us; speedup vs baseline: 8.4814x; 1.3382x over previous
//
#include <hip/hip_runtime.h>

#define HW 16384
#define EPSF 1e-5f

typedef __attribute__((ext_vector_type(8))) short s8v;     // 8 bf16 (4 VGPRs)
typedef __attribute__((ext_vector_type(16))) float f16v;   // 32x32 accum

__device__ __forceinline__ ushort f2b(float f) {           // fp32 -> bf16 RNE
    union { float f; unsigned u; } v; v.f = f;
    return (ushort)((v.u + 0x7FFFu + ((v.u >> 16) & 1u)) >> 16);
}
__device__ __forceinline__ float b2f(ushort h) {
    union { unsigned u; float f; } v; v.u = ((unsigned)h) << 16; return v.f;
}

// out-region map (ushort offsets into d_out):
//   A-half of out-batch k (ch 0:64):   k*4194304 .. +2097152 ushorts (4 MB)
//   B-half of out-batch k (ch 64:128): k*4194304 + 2097152 (4 MB)
// c1[local j] (8 MB) -> A-halves of out-batches 2j, 2j+1 (row piece = y>>6)
// c2[b] bf16 NHWC    -> B-half of batch b
// edge[b] bf16 NHWC  -> A-half of batch b (after c1 dead)

// ---------------- BN folding
__global__ void bn_prep(const float* __restrict__ b1, const float* __restrict__ g1,
                        const float* __restrict__ be1, const float* __restrict__ m1,
                        const float* __restrict__ v1,
                        const float* __restrict__ b2, const float* __restrict__ g2,
                        const float* __restrict__ be2, const float* __restrict__ m2,
                        const float* __restrict__ v2,
                        const float* __restrict__ b3, const float* __restrict__ g3,
                        const float* __restrict__ be3, const float* __restrict__ m3,
                        const float* __restrict__ v3,
                        float* __restrict__ ws) {
    int t = threadIdx.x;
    if (t < 256) { float a = g1[t] * rsqrtf(v1[t] + EPSF); ws[t] = a;       ws[256 + t] = (b1[t] - m1[t]) * a + be1[t]; }
    if (t < 128) { float a = g2[t] * rsqrtf(v2[t] + EPSF); ws[512 + t] = a; ws[640 + t] = (b2[t] - m2[t]) * a + be2[t]; }
    if (t < 64)  { float a = g3[t] * rsqrtf(v3[t] + EPSF); ws[768 + t] = a; ws[832 + t] = (b3[t] - m3[t]) * a + be3[t]; }
}

// ---------------- weight repack fp32 OIHW -> bf16 [off][co][ci]
__global__ __launch_bounds__(256) void wprep(const float* __restrict__ w2, const float* __restrict__ w3,
                                             ushort* __restrict__ w2b, ushort* __restrict__ w3b) {
    int t = blockIdx.x * 256 + threadIdx.x;
    if (t < 9 * 128 * 256) {
        int off = t >> 15; int r = t & 32767; int co = r >> 8; int ci = r & 255;
        w2b[t] = f2b(w2[(co * 256 + ci) * 9 + off]);
    }
    t -= 9 * 128 * 256;
    if (t >= 0 && t < 9 * 64 * 128) {
        int off = t >> 13; int r = t & 8191; int co = r >> 7; int ci = r & 127;
        w3b[t] = f2b(w3[(co * 128 + ci) * 9 + off]);
    }
}

// ---------------- concat part 1 (runs LAST): out[b, 0:64] = input[b]
__global__ __launch_bounds__(256) void copy_in_k(const float* __restrict__ x, float* __restrict__ out) {
    size_t i = (size_t)blockIdx.x * 256 + threadIdx.x;
    size_t b = i >> 18;
    size_t r = i & 262143;
    ((float4*)out)[b * (size_t)(128 * HW / 4) + r] = ((const float4*)x)[i];
}

// ---------------- conv1x1 (64 -> 256) + BN + ReLU, fp32 math, NHWC bf16 -> out A-halves
__global__ __launch_bounds__(256)
void conv1_nhwc(const float* __restrict__ x, const float* __restrict__ w,
                const float* __restrict__ alpha, const float* __restrict__ beta,
                ushort* __restrict__ c1u, int b0) {
    const int tid = threadIdx.x;
    const int pg = tid & 31;        // 4-px group
    const int cog = tid >> 5;       // 8-co group
    const int y = blockIdx.x & 127;
    const int coblk = blockIdx.x >> 7;   // 0..3
    const int bz = blockIdx.y;           // chunk-local batch 0..7
    const int co0 = coblk * 64 + cog * 8;
    const float* xp = x + (size_t)(b0 + bz) * 64 * HW + y * 128 + pg * 4;
    float acc[8][4];
#pragma unroll
    for (int j = 0; j < 8; ++j)
#pragma unroll
        for (int i = 0; i < 4; ++i) acc[j][i] = 0.f;
#pragma unroll 4
    for (int ci = 0; ci < 64; ++ci) {
        const float4 xv = *(const float4*)(xp + (size_t)ci * HW);
#pragma unroll
        for (int j = 0; j < 8; ++j) {
            const float wv = w[(co0 + j) * 64 + ci];
            acc[j][0] += wv * xv.x; acc[j][1] += wv * xv.y;
            acc[j][2] += wv * xv.z; acc[j][3] += wv * xv.w;
        }
    }
    const float4 a0 = *(const float4*)&alpha[co0], a1 = *(const float4*)&alpha[co0 + 4];
    const float4 b0v = *(const float4*)&beta[co0], b1v = *(const float4*)&beta[co0 + 4];
    const float av[8] = {a0.x, a0.y, a0.z, a0.w, a1.x, a1.y, a1.z, a1.w};
    const float bv[8] = {b0v.x, b0v.y, b0v.z, b0v.w, b1v.x, b1v.y, b1v.z, b1v.w};
    const int piece = y >> 6;
    const size_t base = (size_t)(2 * bz + piece) * 4194304;
#pragma unroll
    for (int i = 0; i < 4; ++i) {
        union { ushort s[8]; int4 v; } o;
#pragma unroll
        for (int j = 0; j < 8; ++j)
            o.s[j] = f2b(fmaxf(acc[j][i] * av[j] + bv[j], 0.f));
        const int xx = pg * 4 + i;
        *(int4*)&c1u[base + (((y & 63) * 128 + xx) * 256 + co0)] = o.v;
    }
}

// ---------------- conv2: 3x3, 256->128, implicit-GEMM MFMA (bf16)
// reads c1 from out A-halves (piece-split rows), writes c2 bf16 into out B-half.
__global__ __launch_bounds__(256, 2)
void conv2_mfma(const ushort* __restrict__ c1u, const ushort* __restrict__ wb,
                const float* __restrict__ alpha, const float* __restrict__ beta,
                ushort* __restrict__ ybf, int b0) {
    constexpr int CI = 256, CO = 128, MT = 2;
    __shared__ __align__(16) ushort sX[2][130][40];   // [row][px+1][ci32 pad40]
    __shared__ __align__(16) ushort sW[CO][40];
    const int tid = threadIdx.x;
    const int lane = tid & 63;
    const int wid = tid >> 6;
    const int wm = wid & 1;
    const int wr = wid >> 1;
    const int l31 = lane & 31;
    const int l5 = lane >> 5;
    const int bz = blockIdx.x >> 6;                   // chunk-local batch 0..7
    const int y0 = (blockIdx.x & 63) * 2;

    f16v acc[MT][4];
#pragma unroll
    for (int mt = 0; mt < MT; ++mt)
#pragma unroll
        for (int nt = 0; nt < 4; ++nt) acc[mt][nt] = (f16v)(0.0f);

    if (tid < 160) {       // zero x-halo pads once
        int r = tid / 80, rem = tid - r * 80;
        int p = (rem < 40) ? 0 : 129;
        sX[r][p][rem % 40] = 0;
    }

    for (int dy = 0; dy < 3; ++dy) {
        for (int cc = 0; cc < CI; cc += 32) {
            __syncthreads();
#pragma unroll
            for (int it = 0; it < 4; ++it) {
                const int idx = it * 256 + tid;
                const int r = idx >> 9, xx = (idx >> 2) & 127, cig = idx & 3;
                const int yy = y0 + r + dy - 1;
                int4 v = make_int4(0, 0, 0, 0);
                if ((unsigned)yy < 128u) {
                    const size_t base = (size_t)(2 * bz + (yy >> 6)) * 4194304;
                    v = *(const int4*)&c1u[base + (((yy & 63) * 128 + xx) * 256 + cc + cig * 8)];
                }
                *(int4*)&sX[r][xx + 1][cig * 8] = v;
            }
            for (int dx = 0; dx < 3; ++dx) {
                if (dx) __syncthreads();
                const int off = dy * 3 + dx;
#pragma unroll
                for (int it = 0; it < 2; ++it) {
                    const int idx = it * 256 + tid;
                    const int co = idx >> 2, cig = idx & 3;
                    *(int4*)&sW[co][cig * 8] =
                        *(const int4*)&wb[((size_t)(off * CO) + co) * CI + cc + cig * 8];
                }
                __syncthreads();
#pragma unroll
                for (int kh = 0; kh < 2; ++kh) {
                    s8v af[MT], bfr[4];
#pragma unroll
                    for (int mt = 0; mt < MT; ++mt)
                        af[mt] = *(const s8v*)&sW[wm * 64 + mt * 32 + l31][kh * 16 + l5 * 8];
#pragma unroll
                    for (int nt = 0; nt < 4; ++nt)
                        bfr[nt] = *(const s8v*)&sX[wr][nt * 32 + l31 + dx][kh * 16 + l5 * 8];
#pragma unroll
                    for (int mt = 0; mt < MT; ++mt)
#pragma unroll
                        for (int nt = 0; nt < 4; ++nt)
                            acc[mt][nt] = __builtin_amdgcn_mfma_f32_32x32x16_bf16(
                                af[mt], bfr[nt], acc[mt][nt], 0, 0, 0);
                }
            }
        }
    }
    const int yy = y0 + wr;
    const size_t cb2 = (size_t)(b0 + bz) * 4194304 + 2097152;   // B-half ushort base
#pragma unroll
    for (int mt = 0; mt < MT; ++mt) {
#pragma unroll
        for (int nt = 0; nt < 4; ++nt) {
            const int xx = nt * 32 + l31;
#pragma unroll
            for (int rg = 0; rg < 4; ++rg) {
                const int co0 = wm * 64 + mt * 32 + rg * 8 + l5 * 4;
                const float4 av = *(const float4*)&alpha[co0];
                const float4 bv = *(const float4*)&beta[co0];
                ushort4 o;
                o.x = f2b(fmaxf(acc[mt][nt][rg * 4 + 0] * av.x + bv.x, 0.f));
                o.y = f2b(fmaxf(acc[mt][nt][rg * 4 + 1] * av.y + bv.y, 0.f));
                o.z = f2b(fmaxf(acc[mt][nt][rg * 4 + 2] * av.z + bv.z, 0.f));
                o.w = f2b(fmaxf(acc[mt][nt][rg * 4 + 3] * av.w + bv.w, 0.f));
                *(ushort4*)&ybf[cb2 + ((size_t)yy * 128 + xx) * 128 + co0] = o;
            }
        }
    }
}

// ---------------- sobel depthwise, c2 (out B-half) -> edge (out A-half), bf16 NHWC
__global__ __launch_bounds__(256)
void sobel_nhwc(const ushort* __restrict__ outu, ushort* __restrict__ edgeu) {
    const int tid = threadIdx.x;
    const int cg = tid & 15;        // 8-channel group
    const int xl = tid >> 4;        // 16 px per block
    const int xblk = blockIdx.x & 7;
    const int y = (blockIdx.x >> 3) & 127;
    const int b = blockIdx.x >> 10;
    const int x = xblk * 16 + xl;
    const size_t cb2 = (size_t)b * 4194304 + 2097152;
    const size_t eb = (size_t)b * 4194304;
    float acc[8];
#pragma unroll
    for (int j = 0; j < 8; ++j) acc[j] = 0.f;
    const float cf[9] = {2.f, 4.f, 4.f, -2.f, 0.f, 2.f, -4.f, -4.f, -2.f};
#pragma unroll
    for (int t = 0; t < 9; ++t) {
        if (t == 4) continue;
        const int yy = y + (t / 3) - 1, xx = x + (t % 3) - 1;
        if ((unsigned)yy < 128u && (unsigned)xx < 128u) {
            union { int4 v; ushort s[8]; } u;
            u.v = *(const int4*)&outu[cb2 + ((size_t)yy * 128 + xx) * 128 + cg * 8];
            const float c = cf[t];
#pragma unroll
            for (int j = 0; j < 8; ++j) acc[j] += c * b2f(u.s[j]);
        }
    }
    union { ushort s[8]; int4 v; } o;
#pragma unroll
    for (int j = 0; j < 8; ++j) o.s[j] = f2b(acc[j]);
    *(int4*)&edgeu[eb + ((size_t)y * 128 + x) * 128 + cg * 8] = o.v;
}

// ---------------- conv3: 3x3, 128->64, implicit-GEMM MFMA; edge (out A-half) -> out fp32 ch64:128
__global__ __launch_bounds__(256, 2)
void conv3_mfma(const ushort* __restrict__ edgeu, const ushort* __restrict__ wb,
                const float* __restrict__ alpha, const float* __restrict__ beta,
                float* __restrict__ out) {
    constexpr int CI = 128, CO = 64;
    __shared__ __align__(16) ushort sX[2][130][40];
    __shared__ __align__(16) ushort sW[CO][40];
    const int tid = threadIdx.x;
    const int lane = tid & 63;
    const int wid = tid >> 6;
    const int wm = wid & 1;        // co half (32)
    const int wr = wid >> 1;       // row
    const int l31 = lane & 31;
    const int l5 = lane >> 5;
    const int b = blockIdx.x >> 6;
    const int y0 = (blockIdx.x & 63) * 2;
    const size_t eb = (size_t)b * 4194304;

    f16v acc[4];
#pragma unroll
    for (int nt = 0; nt < 4; ++nt) acc[nt] = (f16v)(0.0f);

    if (tid < 160) {
        int r = tid / 80, rem = tid - r * 80;
        int p = (rem < 40) ? 0 : 129;
        sX[r][p][rem % 40] = 0;
    }

    for (int dy = 0; dy < 3; ++dy) {
        for (int cc = 0; cc < CI; cc += 32) {
            __syncthreads();
#pragma unroll
            for (int it = 0; it < 4; ++it) {
                const int idx = it * 256 + tid;
                const int r = idx >> 9, xx = (idx >> 2) & 127, cig = idx & 3;
                const int yy = y0 + r + dy - 1;
                int4 v = make_int4(0, 0, 0, 0);
                if ((unsigned)yy < 128u)
                    v = *(const int4*)&edgeu[eb + ((size_t)yy * 128 + xx) * CI + cc + cig * 8];
                *(int4*)&sX[r][xx + 1][cig * 8] = v;
            }
            for (int dx = 0; dx < 3; ++dx) {
                if (dx) __syncthreads();
                const int off = dy * 3 + dx;
                {   // 64 co x 4 cig = 256 tasks
                    const int co = tid >> 2, cig = tid & 3;
                    *(int4*)&sW[co][cig * 8] =
                        *(const int4*)&wb[((size_t)(off * CO) + co) * CI + cc + cig * 8];
                }
                __syncthreads();
#pragma unroll
                for (int kh = 0; kh < 2; ++kh) {
                    const s8v af = *(const s8v*)&sW[wm * 32 + l31][kh * 16 + l5 * 8];
                    s8v bfr[4];
#pragma unroll
                    for (int nt = 0; nt < 4; ++nt)
                        bfr[nt] = *(const s8v*)&sX[wr][nt * 32 + l31 + dx][kh * 16 + l5 * 8];
#pragma unroll
                    for (int nt = 0; nt < 4; ++nt)
                        acc[nt] = __builtin_amdgcn_mfma_f32_32x32x16_bf16(af, bfr[nt], acc[nt], 0, 0, 0);
                }
            }
        }
    }
    const int yy = y0 + wr;
#pragma unroll
    for (int nt = 0; nt < 4; ++nt) {
        const int xx = nt * 32 + l31;
#pragma unroll
        for (int rg = 0; rg < 4; ++rg) {
            const int co0 = wm * 32 + rg * 8 + l5 * 4;
            const float4 av = *(const float4*)&alpha[co0];
            const float4 bv = *(const float4*)&beta[co0];
            const size_t base = ((size_t)b * 128 + 64 + co0) * HW + yy * 128 + xx;
            out[base]          = fmaxf(acc[nt][rg * 4 + 0] * av.x + bv.x, 0.f);
            out[base + HW]     = fmaxf(acc[nt][rg * 4 + 1] * av.y + bv.y, 0.f);
            out[base + 2 * HW] = fmaxf(acc[nt][rg * 4 + 2] * av.z + bv.z, 0.f);
            out[base + 3 * HW] = fmaxf(acc[nt][rg * 4 + 3] * av.w + bv.w, 0.f);
        }
    }
}

extern "C" void kernel_launch(void* const* d_in, const int* in_sizes, int n_in,
                              void* d_out, int out_size, void* d_ws, size_t ws_size,
                              hipStream_t stream) {
    const float* input = (const float*)d_in[0];
    const float* w1 = (const float*)d_in[1];
    const float* b1 = (const float*)d_in[2];
    const float* g1 = (const float*)d_in[3];
    const float* be1 = (const float*)d_in[4];
    const float* m1 = (const float*)d_in[5];
    const float* v1 = (const float*)d_in[6];
    const float* w2 = (const float*)d_in[7];
    const float* b2 = (const float*)d_in[8];
    const float* g2 = (const float*)d_in[9];
    const float* be2 = (const float*)d_in[10];
    const float* m2 = (const float*)d_in[11];
    const float* v2 = (const float*)d_in[12];
    const float* w3 = (const float*)d_in[13];
    const float* b3 = (const float*)d_in[14];
    const float* g3 = (const float*)d_in[15];
    const float* be3 = (const float*)d_in[16];
    const float* m3 = (const float*)d_in[17];
    const float* v3 = (const float*)d_in[18];
    float* ws = (float*)d_ws;
    float* out = (float*)d_out;
    ushort* outu = (ushort*)d_out;

    float* A1 = ws;        float* B1 = ws + 256;
    float* A2 = ws + 512;  float* B2 = ws + 640;
    float* A3 = ws + 768;  float* B3 = ws + 832;

    char* wsb = (char*)d_ws;
    ushort* w2b = (ushort*)(wsb + 4096);                 // 589824 B
    ushort* w3b = (ushort*)(wsb + 4096 + 589824);        // 147456 B; total ws use < 1 MB

    bn_prep<<<1, 256, 0, stream>>>(b1, g1, be1, m1, v1, b2, g2, be2, m2, v2,
                                   b3, g3, be3, m3, v3, ws);
    wprep<<<1440, 256, 0, stream>>>(w2, w3, w2b, w3b);

    // phase A: c1 -> out A-halves (8 batches/iter), c2 -> out B-halves
    for (int b0 = 0; b0 < 16; b0 += 8) {
        conv1_nhwc<<<dim3(512, 8), 256, 0, stream>>>(input, w1, A1, B1, outu, b0);
        conv2_mfma<<<512, 256, 0, stream>>>(outu, w2b, A2, B2, outu, b0);
    }
    // phase B: full-batch fat dispatches
    sobel_nhwc<<<16384, 256, 0, stream>>>(outu, outu);
    conv3_mfma<<<1024, 256, 0, stream>>>(outu, w3b, A3, B3, out);
    copy_in_k<<<16384, 256, 0, stream>>>(input, out);
}